// Round 1
// baseline (817.120 us; speedup 1.0000x reference)
//
#include <hip/hip_runtime.h>
#include <stdint.h>

#define DIMD 512
#define BATCH 512
#define KSAMP 10
#define NCLS 8192
#define TREJ 32

// ---------------- RNG (counter-based, deterministic) ----------------
__device__ inline uint64_t sm64(uint64_t x) {
  x += 0x9E3779B97F4A7C15ull;
  x = (x ^ (x >> 30)) * 0xBF58476D1CE4E5B9ull;
  x = (x ^ (x >> 27)) * 0x94D049BB133111EBull;
  return x ^ (x >> 31);
}
__device__ inline float u01(uint32_t u) {
  return ((float)u + 0.5f) * 2.3283064365386963e-10f; // 2^-32, in (0,1)
}
__device__ inline float normal_from(uint64_t r) {
  float u1 = u01((uint32_t)(r >> 32));
  float u2 = u01((uint32_t)r);
  return sqrtf(-2.0f * __logf(u1)) * __cosf(6.28318530718f * u2);
}

// Gamma(255.5) via Marsaglia-Tsang (exact rejection, accept ~0.998)
__device__ inline float gamma255(uint64_t& ctr) {
  const float dg = 255.1666667f;      // a - 1/3
  const float cg = 0.02086730f;       // 1/(3 sqrt(dg))
  for (int i = 0; i < 16; i++) {
    uint64_t r = sm64(ctr++);
    float x = normal_from(r);
    float t = fmaf(cg, x, 1.0f);
    if (t <= 0.0f) continue;
    float v3 = t * t * t;
    uint64_t r2 = sm64(ctr++);
    float u3 = u01((uint32_t)(r2 >> 32));
    if (__logf(u3) < 0.5f * x * x + dg * (1.0f - v3 + __logf(v3))) return dg * v3;
  }
  return dg;
}

__device__ inline float wave_sum(float v) {
  #pragma unroll
  for (int o = 32; o > 0; o >>= 1) v += __shfl_down(v, o, 64);
  return __shfl(v, 0, 64);
}

// accurate-ish logc for prep (called O(C) times)
__device__ inline float vmf_logc(float k) {
  float k2 = k * k;
  float sm = sqrtf(65280.25f + k2);   // 255.5^2
  float sp = sqrtf(65792.25f + k2);   // 256.5^2
  return 127.75f * (logf(255.5f + sm) + logf(255.5f + sp)) - 0.5f * (sm + sp);
}

// ---------------- kernels ----------------
__global__ __launch_bounds__(256) void zero_kernel(float4* __restrict__ out4,
                                                   float* __restrict__ small) {
  int i = blockIdx.x * 256 + threadIdx.x;       // grid = 4096*256 = 1,048,576 = out float4 count
  out4[i] = make_float4(0.f, 0.f, 0.f, 0.f);
  if (i < NCLS * 0 + (BATCH * KSAMP + 1)) small[i] = 0.0f;  // rowsum[5120] + Mslot[1]
}

__global__ __launch_bounds__(256) void prep_w(const float* __restrict__ weight,
                                              const float* __restrict__ lscale,
                                              float* __restrict__ muW,
                                              float* __restrict__ lcw,
                                              float* __restrict__ A2,
                                              float* __restrict__ B2,
                                              float* __restrict__ Msl) {
  __shared__ float red[4];
  int c = blockIdx.x, tid = threadIdx.x;
  const float* wr = weight + (size_t)c * (DIMD + 2) + 1;
  float v0 = wr[tid], v1 = wr[tid + 256];
  float s = wave_sum(v0 * v0 + v1 * v1);
  if ((tid & 63) == 0) red[tid >> 6] = s;
  __syncthreads();
  float tot = red[0] + red[1] + red[2] + red[3];
  float inv = rsqrtf(tot);
  muW[(size_t)c * DIMD + tid]       = v0 * inv;
  muW[(size_t)c * DIMD + tid + 256] = v1 * inv;
  if (tid == 0) {
    float hik = weight[(size_t)c * (DIMD + 2) + DIMD + 1];
    float kw = expf(-hik);
    float k1 = expf(lscale[0]);
    float lw = vmf_logc(kw);
    lcw[c] = lw;
    A2[c] = fmaf(k1, k1, kw * kw);
    B2[c] = 2.0f * k1 * kw;
    float Mc = lw - vmf_logc(k1 + kw);          // upper bound of lcw - logc(kk)
    atomicMax(reinterpret_cast<int*>(Msl), __float_as_int(Mc)); // all Mc > 0
  }
}

__global__ __launch_bounds__(256) void prep_x(const float* __restrict__ params,
                                              float* __restrict__ muX,
                                              float* __restrict__ kapX) {
  __shared__ float red[4];
  int b = blockIdx.x, tid = threadIdx.x;
  const float* pr = params + (size_t)b * (DIMD + 2) + 1;
  float v0 = pr[tid], v1 = pr[tid + 256];
  float s = wave_sum(v0 * v0 + v1 * v1);
  if ((tid & 63) == 0) red[tid >> 6] = s;
  __syncthreads();
  float tot = red[0] + red[1] + red[2] + red[3];
  float inv = rsqrtf(tot);
  muX[(size_t)b * DIMD + tid]       = v0 * inv;
  muX[(size_t)b * DIMD + tid + 256] = v1 * inv;
  if (tid == 0) kapX[b] = expf(-params[(size_t)b * (DIMD + 2) + DIMD + 1]);
}

// one wave per (b,k): Wood's rejection for w, Gaussian tangent, compose sample
__global__ __launch_bounds__(64) void sample_kernel(const float* __restrict__ muX,
                                                    const float* __restrict__ kapX,
                                                    float* __restrict__ S) {
  int row = blockIdx.x;            // b*KSAMP + k
  int b = row / KSAMP;
  int lane = threadIdx.x;
  float mu[8], v[8];
  #pragma unroll
  for (int j = 0; j < 8; j++) mu[j] = muX[(size_t)b * DIMD + j * 64 + lane];
  float kap = kapX[b];
  float bb = (-2.0f * kap + sqrtf(fmaf(4.0f * kap, kap, 511.0f * 511.0f))) / 511.0f;
  float x0 = (1.0f - bb) / (1.0f + bb);
  float cc = kap * x0 + 511.0f * __logf(1.0f - x0 * x0);

  // all 64 lanes run identical scalar rejection (uniform branching)
  uint64_t ctr = ((uint64_t)(row + 1)) << 32;
  float w = 0.0f, w0 = 0.0f;
  bool got = false;
  for (int t = 0; t < TREJ && !got; t++) {
    float g1 = gamma255(ctr);
    float g2 = gamma255(ctr);
    float z = g1 / (g1 + g2);
    float wt = (1.0f - (1.0f + bb) * z) / (1.0f - (1.0f - bb) * z);
    uint64_t r = sm64(ctr++);
    float u = u01((uint32_t)(r >> 32));
    if (t == 0) w0 = wt;
    float lhs = kap * wt + 511.0f * __logf(1.0f - x0 * wt) - cc;
    if (lhs >= __logf(fmaxf(u, 1e-10f))) { w = wt; got = true; }
  }
  if (!got) w = w0;

  uint64_t cbase = (((uint64_t)(row + 1)) << 32) | 0x40000000ull;
  #pragma unroll
  for (int j = 0; j < 8; j++) v[j] = normal_from(sm64(cbase + (uint64_t)(j * 64 + lane)));
  float d = 0.0f;
  #pragma unroll
  for (int j = 0; j < 8; j++) d += v[j] * mu[j];
  d = wave_sum(d);
  float n2 = 0.0f;
  #pragma unroll
  for (int j = 0; j < 8; j++) { v[j] -= d * mu[j]; n2 += v[j] * v[j]; }
  n2 = wave_sum(n2);
  float ivn = rsqrtf(n2);
  float st = sqrtf(fmaxf(0.0f, 1.0f - w * w)) * ivn;
  float sv[8];
  float s2 = 0.0f;
  #pragma unroll
  for (int j = 0; j < 8; j++) { sv[j] = fmaf(st, v[j], w * mu[j]); s2 += sv[j] * sv[j]; }
  s2 = wave_sum(s2);
  float is = rsqrtf(s2);
  #pragma unroll
  for (int j = 0; j < 8; j++) S[(size_t)row * DIMD + j * 64 + lane] = sv[j] * is;
}

// fused: cos GEMM (64x64 tile, 4x4 microtile) + logC transform + exp + row partial sums
__global__ __launch_bounds__(256) void gemm_lse(const float* __restrict__ S,
                                                const float* __restrict__ W,
                                                const float* __restrict__ lcw,
                                                const float* __restrict__ A2,
                                                const float* __restrict__ B2,
                                                const float* __restrict__ Msl,
                                                float* __restrict__ rowsum) {
  __shared__ float As[16 * 68];   // [kk][row], stride 68 keeps float4 alignment + kills conflicts
  __shared__ float Bs[16 * 68];
  int tid = threadIdx.x;
  int tx = tid & 15, ty = tid >> 4;
  int c0 = blockIdx.x * 64;
  int r0 = blockIdx.y * 64;
  int lr = tid >> 4, lk = tid & 15;

  float acc[4][4];
  #pragma unroll
  for (int i = 0; i < 4; i++)
    #pragma unroll
    for (int j = 0; j < 4; j++) acc[i][j] = 0.0f;

  for (int kt = 0; kt < DIMD; kt += 16) {
    #pragma unroll
    for (int i = 0; i < 4; i++) {
      As[lk * 68 + lr + i * 16] = S[(size_t)(r0 + lr + i * 16) * DIMD + kt + lk];
      Bs[lk * 68 + lr + i * 16] = W[(size_t)(c0 + lr + i * 16) * DIMD + kt + lk];
    }
    __syncthreads();
    #pragma unroll
    for (int kk = 0; kk < 16; kk++) {
      float4 a4 = *(const float4*)&As[kk * 68 + ty * 4];
      float4 b4 = *(const float4*)&Bs[kk * 68 + tx * 4];
      float av[4] = {a4.x, a4.y, a4.z, a4.w};
      float bv[4] = {b4.x, b4.y, b4.z, b4.w};
      #pragma unroll
      for (int i = 0; i < 4; i++)
        #pragma unroll
        for (int j = 0; j < 4; j++) acc[i][j] = fmaf(av[i], bv[j], acc[i][j]);
    }
    __syncthreads();
  }

  float Msh = Msl[0];
  float4 lc4 = *(const float4*)&lcw[c0 + tx * 4];
  float4 a24 = *(const float4*)&A2[c0 + tx * 4];
  float4 b24 = *(const float4*)&B2[c0 + tx * 4];
  float lcv[4] = {lc4.x, lc4.y, lc4.z, lc4.w};
  float A2v[4] = {a24.x, a24.y, a24.z, a24.w};
  float B2v[4] = {b24.x, b24.y, b24.z, b24.w};

  #pragma unroll
  for (int i = 0; i < 4; i++) {
    float s = 0.0f;
    #pragma unroll
    for (int j = 0; j < 4; j++) {
      float kk2 = fmaf(B2v[j], acc[i][j], A2v[j]);          // kk^2 = k1^2+k2^2+2k1k2cos
      float sm = sqrtf(65280.25f + kk2);
      float sp = sqrtf(65792.25f + kk2);
      float lkk = 127.75f * (__logf(255.5f + sm) + __logf(255.5f + sp)) - 0.5f * (sm + sp);
      s += __expf(lcv[j] - lkk - Msh);
    }
    // reduce over tx (16 lanes) with xor-shuffles; lanes differ only in low 4 bits
    #pragma unroll
    for (int o = 1; o < 16; o <<= 1) s += __shfl_xor(s, o, 64);
    if (tx == 0) atomicAdd(&rowsum[r0 + ty * 4 + i], s);
  }
}

__global__ __launch_bounds__(64) void finalize_kernel(const float* __restrict__ muX,
                                                      const float* __restrict__ muW,
                                                      const float* __restrict__ rowsum,
                                                      const float* __restrict__ Msl,
                                                      const int* __restrict__ labels,
                                                      const float* __restrict__ lscale,
                                                      float* __restrict__ out) {
  int b = blockIdx.x;
  int lane = threadIdx.x;
  int lab = labels[b];
  float d = 0.0f;
  #pragma unroll
  for (int j = 0; j < 8; j++)
    d += muX[(size_t)b * DIMD + j * 64 + lane] * muW[(size_t)lab * DIMD + j * 64 + lane];
  d = wave_sum(d);
  if (lane == 0) {
    float k1 = expf(lscale[0]);
    float acc = 0.0f;
    #pragma unroll
    for (int k = 0; k < KSAMP; k++) acc += __logf(rowsum[b * KSAMP + k]);
    // neg_logden[b,k] = M' + log(rowsum);  logc(k1) cancels with -logc(scale)
    float loss = Msl[0] + acc * (1.0f / KSAMP) - k1 * d;
    out[(size_t)b * NCLS + lab] = -loss;
  }
}

// ---------------- launch ----------------
extern "C" void kernel_launch(void* const* d_in, const int* in_sizes, int n_in,
                              void* d_out, int out_size, void* d_ws, size_t ws_size,
                              hipStream_t stream) {
  const float* params = (const float*)d_in[0];   // (512, 514) fp32
  const float* weight = (const float*)d_in[1];   // (8192, 514) fp32
  const float* lscale = (const float*)d_in[2];   // scalar fp32
  const int*   labels = (const int*)d_in[3];     // (512,) int32
  float* out = (float*)d_out;                    // (512, 8192) fp32
  float* ws = (float*)d_ws;

  // ws layout (float offsets)
  float* muW    = ws;                 // 512*8192   = 4,194,304
  float* S      = ws + 4194304;       // 5120*512   = 2,621,440
  float* muX    = ws + 6815744;       // 512*512    =   262,144
  float* kapX   = ws + 7077888;       // 512
  float* lcw    = ws + 7078400;       // 8192
  float* A2     = ws + 7086592;       // 8192
  float* B2     = ws + 7094784;       // 8192
  float* rowsum = ws + 7102976;       // 5120
  // Mslot = ws + 7108096 (contiguous after rowsum; zeroed together)
  float* Msl    = ws + 7108096;       // 1

  hipLaunchKernelGGL(zero_kernel, dim3(4096), dim3(256), 0, stream,
                     (float4*)out, rowsum);
  hipLaunchKernelGGL(prep_w, dim3(NCLS), dim3(256), 0, stream,
                     weight, lscale, muW, lcw, A2, B2, Msl);
  hipLaunchKernelGGL(prep_x, dim3(BATCH), dim3(256), 0, stream,
                     params, muX, kapX);
  hipLaunchKernelGGL(sample_kernel, dim3(BATCH * KSAMP), dim3(64), 0, stream,
                     muX, kapX, S);
  hipLaunchKernelGGL(gemm_lse, dim3(NCLS / 64, (BATCH * KSAMP) / 64), dim3(256), 0, stream,
                     S, muW, lcw, A2, B2, Msl, rowsum);
  hipLaunchKernelGGL(finalize_kernel, dim3(BATCH), dim3(64), 0, stream,
                     muX, muW, rowsum, Msl, labels, lscale, out);
}

// Round 2
// 294.189 us; speedup vs baseline: 2.7775x; 2.7775x over previous
//
#include <hip/hip_runtime.h>
#include <stdint.h>

#define DIMD 512
#define BATCH 512
#define KSAMP 10
#define NCLS 8192
#define TREJ 32

typedef __bf16 bf16x8 __attribute__((ext_vector_type(8)));
typedef float f32x4 __attribute__((ext_vector_type(4)));

// ---------------- RNG (counter-based, deterministic) ----------------
__device__ inline uint64_t sm64(uint64_t x) {
  x += 0x9E3779B97F4A7C15ull;
  x = (x ^ (x >> 30)) * 0xBF58476D1CE4E5B9ull;
  x = (x ^ (x >> 27)) * 0x94D049BB133111EBull;
  return x ^ (x >> 31);
}
__device__ inline float u01(uint32_t u) {
  return ((float)u + 0.5f) * 2.3283064365386963e-10f;
}
__device__ inline float normal_from(uint64_t r) {
  float u1 = u01((uint32_t)(r >> 32));
  float u2 = u01((uint32_t)r);
  return sqrtf(-2.0f * __logf(u1)) * __cosf(6.28318530718f * u2);
}
__device__ inline float gamma255(uint64_t& ctr) {
  const float dg = 255.1666667f;
  const float cg = 0.02086730f;
  for (int i = 0; i < 16; i++) {
    uint64_t r = sm64(ctr++);
    float x = normal_from(r);
    float t = fmaf(cg, x, 1.0f);
    if (t <= 0.0f) continue;
    float v3 = t * t * t;
    uint64_t r2 = sm64(ctr++);
    float u3 = u01((uint32_t)(r2 >> 32));
    if (__logf(u3) < 0.5f * x * x + dg * (1.0f - v3 + __logf(v3))) return dg * v3;
  }
  return dg;
}
__device__ inline float wave_sum(float v) {
  #pragma unroll
  for (int o = 32; o > 0; o >>= 1) v += __shfl_down(v, o, 64);
  return __shfl(v, 0, 64);
}
__device__ inline float vmf_logc(float k) {
  float k2 = k * k;
  float sm = sqrtf(65280.25f + k2);
  float sp = sqrtf(65792.25f + k2);
  return 127.75f * (logf(255.5f + sm) + logf(255.5f + sp)) - 0.5f * (sm + sp);
}
__device__ inline unsigned short f2bf(float f) {
  uint32_t u = __float_as_uint(f);
  uint32_t r = (u + 0x7FFFu + ((u >> 16) & 1u)) >> 16;
  return (unsigned short)r;
}
__device__ inline float bf2f(unsigned short s) {
  return __uint_as_float(((uint32_t)s) << 16);
}
__device__ inline void async16(const unsigned short* g, unsigned short* l) {
  __builtin_amdgcn_global_load_lds(
      (const __attribute__((address_space(1))) unsigned int*)g,
      (__attribute__((address_space(3))) unsigned int*)l, 16, 0, 0);
}

// ---------------- kernels ----------------
__global__ __launch_bounds__(256) void zero_kernel(float4* __restrict__ out4,
                                                   float* __restrict__ small) {
  int i = blockIdx.x * 256 + threadIdx.x;
  out4[i] = make_float4(0.f, 0.f, 0.f, 0.f);
  if (i < (BATCH * KSAMP + 1)) small[i] = 0.0f;   // rowsum[5120] + Msl[1]
}

__global__ __launch_bounds__(256) void prep_w(const float* __restrict__ weight,
                                              const float* __restrict__ lscale,
                                              unsigned short* __restrict__ muWb,
                                              float4* __restrict__ cparams,
                                              float* __restrict__ Msl) {
  __shared__ float red[4];
  int c = blockIdx.x, tid = threadIdx.x;
  const float* wr = weight + (size_t)c * (DIMD + 2) + 1;
  float v0 = wr[tid], v1 = wr[tid + 256];
  float s = wave_sum(v0 * v0 + v1 * v1);
  if ((tid & 63) == 0) red[tid >> 6] = s;
  __syncthreads();
  float tot = red[0] + red[1] + red[2] + red[3];
  float inv = rsqrtf(tot);
  muWb[(size_t)c * DIMD + tid]       = f2bf(v0 * inv);
  muWb[(size_t)c * DIMD + tid + 256] = f2bf(v1 * inv);
  if (tid == 0) {
    float hik = weight[(size_t)c * (DIMD + 2) + DIMD + 1];
    float kw = expf(-hik);
    float k1 = expf(lscale[0]);
    float lw = vmf_logc(kw);
    cparams[c] = make_float4(fmaf(k1, k1, kw * kw), 2.0f * k1 * kw, lw, 0.0f);
    float Mc = lw - vmf_logc(k1 + kw);
    atomicMax(reinterpret_cast<int*>(Msl), __float_as_int(Mc)); // all Mc > 0
  }
}

__global__ __launch_bounds__(256) void prep_x(const float* __restrict__ params,
                                              float* __restrict__ muX,
                                              float* __restrict__ kapX) {
  __shared__ float red[4];
  int b = blockIdx.x, tid = threadIdx.x;
  const float* pr = params + (size_t)b * (DIMD + 2) + 1;
  float v0 = pr[tid], v1 = pr[tid + 256];
  float s = wave_sum(v0 * v0 + v1 * v1);
  if ((tid & 63) == 0) red[tid >> 6] = s;
  __syncthreads();
  float tot = red[0] + red[1] + red[2] + red[3];
  float inv = rsqrtf(tot);
  muX[(size_t)b * DIMD + tid]       = v0 * inv;
  muX[(size_t)b * DIMD + tid + 256] = v1 * inv;
  if (tid == 0) kapX[b] = expf(-params[(size_t)b * (DIMD + 2) + DIMD + 1]);
}

__global__ __launch_bounds__(64) void sample_kernel(const float* __restrict__ muX,
                                                    const float* __restrict__ kapX,
                                                    unsigned short* __restrict__ Sb) {
  int row = blockIdx.x;            // b*KSAMP + k
  int b = row / KSAMP;
  int lane = threadIdx.x;
  float mu[8], v[8];
  #pragma unroll
  for (int j = 0; j < 8; j++) mu[j] = muX[(size_t)b * DIMD + j * 64 + lane];
  float kap = kapX[b];
  float bb = (-2.0f * kap + sqrtf(fmaf(4.0f * kap, kap, 511.0f * 511.0f))) / 511.0f;
  float x0 = (1.0f - bb) / (1.0f + bb);
  float cc = kap * x0 + 511.0f * __logf(1.0f - x0 * x0);

  uint64_t ctr = ((uint64_t)(row + 1)) << 32;
  float w = 0.0f, w0 = 0.0f;
  bool got = false;
  for (int t = 0; t < TREJ && !got; t++) {
    float g1 = gamma255(ctr);
    float g2 = gamma255(ctr);
    float z = g1 / (g1 + g2);
    float wt = (1.0f - (1.0f + bb) * z) / (1.0f - (1.0f - bb) * z);
    uint64_t r = sm64(ctr++);
    float u = u01((uint32_t)(r >> 32));
    if (t == 0) w0 = wt;
    float lhs = kap * wt + 511.0f * __logf(1.0f - x0 * wt) - cc;
    if (lhs >= __logf(fmaxf(u, 1e-10f))) { w = wt; got = true; }
  }
  if (!got) w = w0;

  uint64_t cbase = (((uint64_t)(row + 1)) << 32) | 0x40000000ull;
  #pragma unroll
  for (int j = 0; j < 8; j++) v[j] = normal_from(sm64(cbase + (uint64_t)(j * 64 + lane)));
  float d = 0.0f;
  #pragma unroll
  for (int j = 0; j < 8; j++) d += v[j] * mu[j];
  d = wave_sum(d);
  float n2 = 0.0f;
  #pragma unroll
  for (int j = 0; j < 8; j++) { v[j] -= d * mu[j]; n2 += v[j] * v[j]; }
  n2 = wave_sum(n2);
  float ivn = rsqrtf(n2);
  float st = sqrtf(fmaxf(0.0f, 1.0f - w * w)) * ivn;
  float sv[8];
  float s2 = 0.0f;
  #pragma unroll
  for (int j = 0; j < 8; j++) { sv[j] = fmaf(st, v[j], w * mu[j]); s2 += sv[j] * sv[j]; }
  s2 = wave_sum(s2);
  float is = rsqrtf(s2);
  #pragma unroll
  for (int j = 0; j < 8; j++) Sb[(size_t)row * DIMD + j * 64 + lane] = f2bf(sv[j] * is);
}

// MFMA GEMM (bf16, 128x128 tile, BK=32) fused with logC + exp + row partial sums.
// LDS row = 32 bf16 = 64B, 4 k-groups of 16B; k-group swizzle s = g ^ ((row>>1)&3)
// reduces ds_read_b128 phase conflicts from 8-way to 2-way (free per m136).
__global__ __launch_bounds__(256) void gemm_lse(const unsigned short* __restrict__ Sb,
                                                const unsigned short* __restrict__ Wb,
                                                const float4* __restrict__ cparams,
                                                const float* __restrict__ Msl,
                                                float* __restrict__ rowsum) {
  __shared__ __align__(16) unsigned short As[128 * 32];
  __shared__ __align__(16) unsigned short Bs[128 * 32];
  int tid = threadIdx.x;
  int lane = tid & 63, wave = tid >> 6;
  int wm = wave >> 1, wn = wave & 1;
  int tx = lane & 15, tz = lane >> 4;
  int c0 = blockIdx.x * 128;
  int r0 = blockIdx.y * 128;

  // staging geometry: chunk = 16 rows = 1024B; each wave stages 2 chunks of A and B
  int srow = (lane >> 2);                 // 0..15 within chunk
  int kg   = (lane & 3) ^ ((lane >> 3) & 3); // swizzled global k-group this lane fetches
  int ch0 = wave * 2;

  f32x4 acc[4][4];
  #pragma unroll
  for (int i = 0; i < 4; i++)
    #pragma unroll
    for (int j = 0; j < 4; j++) acc[i][j] = (f32x4){0.f, 0.f, 0.f, 0.f};

  for (int kt = 0; kt < DIMD; kt += 32) {
    #pragma unroll
    for (int c = 0; c < 2; c++) {
      int ch = ch0 + c;
      int row = ch * 16 + srow;
      async16(&Sb[(size_t)(r0 + row) * DIMD + kt + kg * 8], &As[ch * 512]);
      async16(&Wb[(size_t)(c0 + row) * DIMD + kt + kg * 8], &Bs[ch * 512]);
    }
    __syncthreads();   // drains vmcnt(0) -> staging complete

    bf16x8 af[4], bf[4];
    #pragma unroll
    for (int mi = 0; mi < 4; mi++) {
      int rA = wm * 64 + mi * 16 + tx;
      int sA = tz ^ ((tx >> 1) & 3);
      af[mi] = *(const bf16x8*)&As[rA * 32 + sA * 8];
      int rB = wn * 64 + mi * 16 + tx;
      bf[mi] = *(const bf16x8*)&Bs[rB * 32 + sA * 8];
    }
    #pragma unroll
    for (int mi = 0; mi < 4; mi++)
      #pragma unroll
      for (int ni = 0; ni < 4; ni++)
        acc[mi][ni] = __builtin_amdgcn_mfma_f32_16x16x32_bf16(af[mi], bf[ni], acc[mi][ni], 0, 0, 0);
    __syncthreads();
  }

  // epilogue: kk2 = A2 + B2*cos; lkk ~ 255.5*log(255.5+sm) - sm + quad(sm)
  float Msh = Msl[0];
  float4 cp[4];
  #pragma unroll
  for (int ni = 0; ni < 4; ni++) cp[ni] = cparams[c0 + wn * 64 + ni * 16 + tx];

  const float CQ2 = -1.3435e-7f, CQ1 = 3.29348e-4f, CQ0 = -0.298669f;
  #pragma unroll
  for (int mi = 0; mi < 4; mi++) {
    #pragma unroll
    for (int reg = 0; reg < 4; reg++) {
      float s = 0.0f;
      #pragma unroll
      for (int ni = 0; ni < 4; ni++) {
        float cosv = acc[mi][ni][reg];
        float kk2 = fmaf(cp[ni].y, cosv, cp[ni].x);
        float sm = sqrtf(65280.25f + kk2);
        float lkk = fmaf(255.5f, __logf(255.5f + sm), -sm)
                  + fmaf(sm, fmaf(sm, CQ2, CQ1), CQ0);
        s += __expf(cp[ni].z - Msh - lkk);
      }
      #pragma unroll
      for (int o = 1; o < 16; o <<= 1) s += __shfl_xor(s, o, 64);
      if (tx == 0)
        atomicAdd(&rowsum[r0 + wm * 64 + mi * 16 + tz * 4 + reg], s);
    }
  }
}

__global__ __launch_bounds__(64) void finalize_kernel(const float* __restrict__ muX,
                                                      const unsigned short* __restrict__ muWb,
                                                      const float* __restrict__ rowsum,
                                                      const float* __restrict__ Msl,
                                                      const int* __restrict__ labels,
                                                      const float* __restrict__ lscale,
                                                      float* __restrict__ out) {
  int b = blockIdx.x;
  int lane = threadIdx.x;
  int lab = labels[b];
  float d = 0.0f;
  #pragma unroll
  for (int j = 0; j < 8; j++)
    d += muX[(size_t)b * DIMD + j * 64 + lane] * bf2f(muWb[(size_t)lab * DIMD + j * 64 + lane]);
  d = wave_sum(d);
  if (lane == 0) {
    float k1 = expf(lscale[0]);
    float acc = 0.0f;
    #pragma unroll
    for (int k = 0; k < KSAMP; k++) acc += __logf(rowsum[b * KSAMP + k]);
    float loss = Msl[0] + acc * (1.0f / KSAMP) - k1 * d;
    out[(size_t)b * NCLS + lab] = -loss;
  }
}

// ---------------- launch ----------------
extern "C" void kernel_launch(void* const* d_in, const int* in_sizes, int n_in,
                              void* d_out, int out_size, void* d_ws, size_t ws_size,
                              hipStream_t stream) {
  const float* params = (const float*)d_in[0];
  const float* weight = (const float*)d_in[1];
  const float* lscale = (const float*)d_in[2];
  const int*   labels = (const int*)d_in[3];
  float* out = (float*)d_out;
  char* ws = (char*)d_ws;

  unsigned short* muWb   = (unsigned short*)(ws);                   // 8192*512*2  = 8,388,608
  unsigned short* Sb     = (unsigned short*)(ws + 8388608);         // 5120*512*2  = 5,242,880
  float*          muX    = (float*)(ws + 13631488);                 // 512*512*4   = 1,048,576
  float*          kapX   = (float*)(ws + 14680064);                 // 2048
  float4*         cparams= (float4*)(ws + 14682112);                // 8192*16     =   131,072
  float*          rowsum = (float*)(ws + 14813184);                 // 5120*4      =    20,480
  float*          Msl    = (float*)(ws + 14833664);                 // 4 (contiguous after rowsum)

  hipLaunchKernelGGL(zero_kernel, dim3(4096), dim3(256), 0, stream,
                     (float4*)out, rowsum);
  hipLaunchKernelGGL(prep_w, dim3(NCLS), dim3(256), 0, stream,
                     weight, lscale, muWb, cparams, Msl);
  hipLaunchKernelGGL(prep_x, dim3(BATCH), dim3(256), 0, stream,
                     params, muX, kapX);
  hipLaunchKernelGGL(sample_kernel, dim3(BATCH * KSAMP), dim3(64), 0, stream,
                     muX, kapX, Sb);
  hipLaunchKernelGGL(gemm_lse, dim3(NCLS / 128, BATCH * KSAMP / 128), dim3(256), 0, stream,
                     Sb, muWb, cparams, Msl, rowsum);
  hipLaunchKernelGGL(finalize_kernel, dim3(BATCH), dim3(64), 0, stream,
                     muX, muWb, rowsum, Msl, labels, lscale, out);
}

// Round 4
// 286.234 us; speedup vs baseline: 2.8547x; 1.0278x over previous
//
#include <hip/hip_runtime.h>
#include <stdint.h>

#define DIMD 512
#define BATCH 512
#define KSAMP 10
#define NCLS 8192
#define TREJ 32

typedef __bf16 bf16x8 __attribute__((ext_vector_type(8)));
typedef float f32x4 __attribute__((ext_vector_type(4)));

// ---------------- RNG (counter-based, deterministic) ----------------
__device__ inline uint64_t sm64(uint64_t x) {
  x += 0x9E3779B97F4A7C15ull;
  x = (x ^ (x >> 30)) * 0xBF58476D1CE4E5B9ull;
  x = (x ^ (x >> 27)) * 0x94D049BB133111EBull;
  return x ^ (x >> 31);
}
__device__ inline float u01(uint32_t u) {
  return ((float)u + 0.5f) * 2.3283064365386963e-10f;
}
__device__ inline float normal_from(uint64_t r) {
  float u1 = u01((uint32_t)(r >> 32));
  float u2 = u01((uint32_t)r);
  return sqrtf(-2.0f * __logf(u1)) * __cosf(6.28318530718f * u2);
}
__device__ inline float gamma255(uint64_t& ctr) {
  const float dg = 255.1666667f;
  const float cg = 0.02086730f;
  for (int i = 0; i < 16; i++) {
    uint64_t r = sm64(ctr++);
    float x = normal_from(r);
    float t = fmaf(cg, x, 1.0f);
    if (t <= 0.0f) continue;
    float v3 = t * t * t;
    uint64_t r2 = sm64(ctr++);
    float u3 = u01((uint32_t)(r2 >> 32));
    if (__logf(u3) < 0.5f * x * x + dg * (1.0f - v3 + __logf(v3))) return dg * v3;
  }
  return dg;
}
__device__ inline float wave_sum(float v) {
  #pragma unroll
  for (int o = 32; o > 0; o >>= 1) v += __shfl_down(v, o, 64);
  return __shfl(v, 0, 64);
}
__device__ inline float vmf_logc(float k) {
  float k2 = k * k;
  float sm = sqrtf(65280.25f + k2);
  float sp = sqrtf(65792.25f + k2);
  return 127.75f * (logf(255.5f + sm) + logf(255.5f + sp)) - 0.5f * (sm + sp);
}
__device__ inline unsigned short f2bf(float f) {
  uint32_t u = __float_as_uint(f);
  uint32_t r = (u + 0x7FFFu + ((u >> 16) & 1u)) >> 16;
  return (unsigned short)r;
}
__device__ inline float bf2f(unsigned short s) {
  return __uint_as_float(((uint32_t)s) << 16);
}
__device__ inline void async16(const unsigned short* g, unsigned short* l) {
  __builtin_amdgcn_global_load_lds(
      (const __attribute__((address_space(1))) unsigned int*)g,
      (__attribute__((address_space(3))) unsigned int*)l, 16, 0, 0);
}

// ---------------- kernels ----------------
// prep_w: normalize class means -> bf16, per-class params, M upper bound,
// PLUS zeroing of out (out = 1,048,576 float4 total -> 128 float4 per block)
// and rowsum. Msl needs no zeroing: poison 0xAAAAAAAA is a negative int and
// all Mc bit-patterns are positive ints, so int-atomicMax recovers.
__global__ __launch_bounds__(256) void prep_w(const float* __restrict__ weight,
                                              const float* __restrict__ lscale,
                                              unsigned short* __restrict__ muWb,
                                              float4* __restrict__ cparams,
                                              float* __restrict__ rowsum,
                                              float* __restrict__ Msl,
                                              float4* __restrict__ out4) {
  __shared__ float red[4];
  int c = blockIdx.x, tid = threadIdx.x;
  // zero this block's 128-float4 slab of out (8192 * 128 = 1,048,576 exactly)
  if (tid < 128) out4[(size_t)c * 128 + tid] = make_float4(0.f, 0.f, 0.f, 0.f);
  if (c < 20) rowsum[c * 256 + tid] = 0.0f;   // 20*256 = 5120

  const float* wr = weight + (size_t)c * (DIMD + 2) + 1;
  float v0 = wr[tid], v1 = wr[tid + 256];
  float s = wave_sum(v0 * v0 + v1 * v1);
  if ((tid & 63) == 0) red[tid >> 6] = s;
  __syncthreads();
  float tot = red[0] + red[1] + red[2] + red[3];
  float inv = rsqrtf(tot);
  muWb[(size_t)c * DIMD + tid]       = f2bf(v0 * inv);
  muWb[(size_t)c * DIMD + tid + 256] = f2bf(v1 * inv);
  if (tid == 0) {
    float hik = weight[(size_t)c * (DIMD + 2) + DIMD + 1];
    float kw = expf(-hik);
    float k1 = expf(lscale[0]);
    float lw = vmf_logc(kw);
    cparams[c] = make_float4(fmaf(k1, k1, kw * kw), 2.0f * k1 * kw, lw, 0.0f);
    float Mc = lw - vmf_logc(k1 + kw);        // > 0 always
    atomicMax(reinterpret_cast<int*>(Msl), __float_as_int(Mc));
  }
}

// sample: 4 rows per block (1 wave per row). Fuses x-normalization.
// Rejection trials run in PARALLEL across lanes 0..31; first accepted wins
// (identical distribution to the reference's argmax-of-accept).
__global__ __launch_bounds__(256) void sample_kernel(const float* __restrict__ params,
                                                     unsigned short* __restrict__ Sb) {
  int wave = threadIdx.x >> 6, lane = threadIdx.x & 63;
  int row = blockIdx.x * 4 + wave;          // b*KSAMP + k
  int b = row / KSAMP;
  const float* pr = params + (size_t)b * (DIMD + 2) + 1;

  float mu[8];
  float n2 = 0.0f;
  #pragma unroll
  for (int j = 0; j < 8; j++) { mu[j] = pr[j * 64 + lane]; n2 += mu[j] * mu[j]; }
  n2 = wave_sum(n2);
  float invn = rsqrtf(n2);
  #pragma unroll
  for (int j = 0; j < 8; j++) mu[j] *= invn;

  float kap = __expf(-pr[DIMD]);            // hidden_ik at col 513
  float bb = (-2.0f * kap + sqrtf(fmaf(4.0f * kap, kap, 511.0f * 511.0f))) / 511.0f;
  float x0 = (1.0f - bb) / (1.0f + bb);
  float cc = kap * x0 + 511.0f * __logf(1.0f - x0 * x0);

  // parallel trials: lane t in [0,32)
  uint64_t ctr = (((uint64_t)(row + 1)) << 32) | ((uint64_t)lane << 8);
  float g1 = gamma255(ctr);
  float g2 = gamma255(ctr);
  float z = g1 / (g1 + g2);
  float wt = (1.0f - (1.0f + bb) * z) / (1.0f - (1.0f - bb) * z);
  uint64_t r = sm64(ctr++);
  float u = u01((uint32_t)(r >> 32));
  float lhs = kap * wt + 511.0f * __logf(1.0f - x0 * wt) - cc;
  bool acc = (lane < TREJ) && (lhs >= __logf(fmaxf(u, 1e-10f)));
  uint64_t mask = __ballot(acc);
  int sel = mask ? (__ffsll((unsigned long long)mask) - 1) : 0;
  float w = __shfl(wt, sel, 64);

  // tangent direction
  uint64_t cbase = (((uint64_t)(row + 1)) << 32) | 0x40000000ull;
  float v[8];
  #pragma unroll
  for (int j = 0; j < 8; j++) v[j] = normal_from(sm64(cbase + (uint64_t)(j * 64 + lane)));
  float d = 0.0f;
  #pragma unroll
  for (int j = 0; j < 8; j++) d += v[j] * mu[j];
  d = wave_sum(d);
  float t2 = 0.0f;
  #pragma unroll
  for (int j = 0; j < 8; j++) { v[j] -= d * mu[j]; t2 += v[j] * v[j]; }
  t2 = wave_sum(t2);
  float ivt = rsqrtf(t2);
  float st = sqrtf(fmaxf(0.0f, 1.0f - w * w)) * ivt;
  float sv[8];
  float s2 = 0.0f;
  #pragma unroll
  for (int j = 0; j < 8; j++) { sv[j] = fmaf(st, v[j], w * mu[j]); s2 += sv[j] * sv[j]; }
  s2 = wave_sum(s2);
  float is = rsqrtf(s2);
  #pragma unroll
  for (int j = 0; j < 8; j++) Sb[(size_t)row * DIMD + j * 64 + lane] = f2bf(sv[j] * is);
}

// MFMA GEMM (bf16, 128x128 tile, BK=32), ping-pong LDS double-buffer with ONE
// barrier per K-iter: next tile's global_load_lds issues right after the
// barrier, so its vmcnt drain hides behind this iter's ds_read+MFMA.
__global__ __launch_bounds__(256) void gemm_lse(const unsigned short* __restrict__ Sb,
                                                const unsigned short* __restrict__ Wb,
                                                const float4* __restrict__ cparams,
                                                const float* __restrict__ Msl,
                                                float* __restrict__ rowsum) {
  __shared__ __align__(16) unsigned short As[2][128 * 32];
  __shared__ __align__(16) unsigned short Bs[2][128 * 32];
  int tid = threadIdx.x;
  int lane = tid & 63, wave = tid >> 6;
  int wm = wave >> 1, wn = wave & 1;
  int tx = lane & 15, tz = lane >> 4;
  int c0 = blockIdx.x * 128;
  int r0 = blockIdx.y * 128;

  // staging geometry: chunk = 16 rows = 1024B; each wave stages 2 chunks of A and B
  int srow = (lane >> 2);                       // 0..15 within chunk
  int kg   = (lane & 3) ^ ((lane >> 3) & 3);    // swizzled global k-group (verified 0-conflict)
  int ch0 = wave * 2;

  f32x4 acc[4][4];
  #pragma unroll
  for (int i = 0; i < 4; i++)
    #pragma unroll
    for (int j = 0; j < 4; j++) acc[i][j] = (f32x4){0.f, 0.f, 0.f, 0.f};

  // prologue: stage kt=0 into buffer 0
  #pragma unroll
  for (int c = 0; c < 2; c++) {
    int ch = ch0 + c, rowi = ch * 16 + srow;
    async16(&Sb[(size_t)(r0 + rowi) * DIMD + kg * 8], &As[0][ch * 512]);
    async16(&Wb[(size_t)(c0 + rowi) * DIMD + kg * 8], &Bs[0][ch * 512]);
  }

  int p = 0;
  for (int kt = 0; kt < DIMD; kt += 32) {
    __syncthreads();   // publishes buf[p]; drains loads issued a full iter ago
    if (kt + 32 < DIMD) {
      #pragma unroll
      for (int c = 0; c < 2; c++) {
        int ch = ch0 + c, rowi = ch * 16 + srow;
        async16(&Sb[(size_t)(r0 + rowi) * DIMD + kt + 32 + kg * 8], &As[p ^ 1][ch * 512]);
        async16(&Wb[(size_t)(c0 + rowi) * DIMD + kt + 32 + kg * 8], &Bs[p ^ 1][ch * 512]);
      }
    }
    bf16x8 af[4], bf[4];
    int sA = tz ^ ((tx >> 1) & 3);
    #pragma unroll
    for (int mi = 0; mi < 4; mi++) {
      int rA = wm * 64 + mi * 16 + tx;
      af[mi] = *(const bf16x8*)&As[p][rA * 32 + sA * 8];
      int rB = wn * 64 + mi * 16 + tx;
      bf[mi] = *(const bf16x8*)&Bs[p][rB * 32 + sA * 8];
    }
    #pragma unroll
    for (int mi = 0; mi < 4; mi++)
      #pragma unroll
      for (int ni = 0; ni < 4; ni++)
        acc[mi][ni] = __builtin_amdgcn_mfma_f32_16x16x32_bf16(af[mi], bf[ni], acc[mi][ni], 0, 0, 0);
    p ^= 1;
  }

  // epilogue: kk2 = A2 + B2*cos; lkk ~ 255.5*log(255.5+sm) - sm + quad(sm)
  float Msh = Msl[0];
  float4 cp[4];
  #pragma unroll
  for (int ni = 0; ni < 4; ni++) cp[ni] = cparams[c0 + wn * 64 + ni * 16 + tx];

  const float CQ2 = -1.3435e-7f, CQ1 = 3.29348e-4f, CQ0 = -0.298669f;
  #pragma unroll
  for (int mi = 0; mi < 4; mi++) {
    #pragma unroll
    for (int reg = 0; reg < 4; reg++) {
      float s = 0.0f;
      #pragma unroll
      for (int ni = 0; ni < 4; ni++) {
        float cosv = acc[mi][ni][reg];
        float kk2 = fmaf(cp[ni].y, cosv, cp[ni].x);
        float sm = sqrtf(65280.25f + kk2);
        float lkk = fmaf(255.5f, __logf(255.5f + sm), -sm)
                  + fmaf(sm, fmaf(sm, CQ2, CQ1), CQ0);
        s += __expf(cp[ni].z - Msh - lkk);
      }
      #pragma unroll
      for (int o = 1; o < 16; o <<= 1) s += __shfl_xor(s, o, 64);
      if (tx == 0)
        atomicAdd(&rowsum[r0 + wm * 64 + mi * 16 + tz * 4 + reg], s);
    }
  }
}

// finalize: renormalizes mu_x from params directly (prep_x fused away)
__global__ __launch_bounds__(64) void finalize_kernel(const float* __restrict__ params,
                                                      const unsigned short* __restrict__ muWb,
                                                      const float* __restrict__ rowsum,
                                                      const float* __restrict__ Msl,
                                                      const int* __restrict__ labels,
                                                      const float* __restrict__ lscale,
                                                      float* __restrict__ out) {
  int b = blockIdx.x;
  int lane = threadIdx.x;
  int lab = labels[b];
  const float* pr = params + (size_t)b * (DIMD + 2) + 1;
  float xv[8];
  float n2 = 0.0f;
  #pragma unroll
  for (int j = 0; j < 8; j++) { xv[j] = pr[j * 64 + lane]; n2 += xv[j] * xv[j]; }
  n2 = wave_sum(n2);
  float invn = rsqrtf(n2);
  float d = 0.0f;
  #pragma unroll
  for (int j = 0; j < 8; j++)
    d += xv[j] * invn * bf2f(muWb[(size_t)lab * DIMD + j * 64 + lane]);
  d = wave_sum(d);
  if (lane == 0) {
    float k1 = expf(lscale[0]);
    float acc = 0.0f;
    #pragma unroll
    for (int k = 0; k < KSAMP; k++) acc += __logf(rowsum[b * KSAMP + k]);
    float loss = Msl[0] + acc * (1.0f / KSAMP) - k1 * d;
    out[(size_t)b * NCLS + lab] = -loss;
  }
}

// ---------------- launch ----------------
extern "C" void kernel_launch(void* const* d_in, const int* in_sizes, int n_in,
                              void* d_out, int out_size, void* d_ws, size_t ws_size,
                              hipStream_t stream) {
  const float* params = (const float*)d_in[0];
  const float* weight = (const float*)d_in[1];
  const float* lscale = (const float*)d_in[2];
  const int*   labels = (const int*)d_in[3];
  float* out = (float*)d_out;
  char* ws = (char*)d_ws;

  unsigned short* muWb   = (unsigned short*)(ws);                   // 8192*512*2  = 8,388,608
  unsigned short* Sb     = (unsigned short*)(ws + 8388608);         // 5120*512*2  = 5,242,880
  float4*         cparams= (float4*)(ws + 13631488);                // 8192*16     =   131,072
  float*          rowsum = (float*)(ws + 13762560);                 // 5120*4      =    20,480
  float*          Msl    = (float*)(ws + 13783040);                 // 4

  hipLaunchKernelGGL(prep_w, dim3(NCLS), dim3(256), 0, stream,
                     weight, lscale, muWb, cparams, rowsum, Msl, (float4*)out);
  hipLaunchKernelGGL(sample_kernel, dim3(BATCH * KSAMP / 4), dim3(256), 0, stream,
                     params, Sb);
  hipLaunchKernelGGL(gemm_lse, dim3(NCLS / 128, BATCH * KSAMP / 128), dim3(256), 0, stream,
                     Sb, muWb, cparams, Msl, rowsum);
  hipLaunchKernelGGL(finalize_kernel, dim3(BATCH), dim3(64), 0, stream,
                     params, muWb, rowsum, Msl, labels, lscale, out);
}

// Round 5
// 179.625 us; speedup vs baseline: 4.5490x; 1.5935x over previous
//
#include <hip/hip_runtime.h>
#include <stdint.h>

#define DIMD 512
#define BATCH 512
#define KSAMP 10
#define NCLS 8192
#define TREJ 32

typedef __bf16 bf16x8 __attribute__((ext_vector_type(8)));
typedef float f32x4 __attribute__((ext_vector_type(4)));

// ---------------- RNG (counter-based, deterministic) ----------------
__device__ inline uint64_t sm64(uint64_t x) {
  x += 0x9E3779B97F4A7C15ull;
  x = (x ^ (x >> 30)) * 0xBF58476D1CE4E5B9ull;
  x = (x ^ (x >> 27)) * 0x94D049BB133111EBull;
  return x ^ (x >> 31);
}
__device__ inline float u01(uint32_t u) {
  return ((float)u + 0.5f) * 2.3283064365386963e-10f;
}
__device__ inline float normal_from(uint64_t r) {
  float u1 = u01((uint32_t)(r >> 32));
  float u2 = u01((uint32_t)r);
  return sqrtf(-2.0f * __logf(u1)) * __cosf(6.28318530718f * u2);
}
__device__ inline float gamma255(uint64_t& ctr) {
  const float dg = 255.1666667f;
  const float cg = 0.02086730f;
  for (int i = 0; i < 16; i++) {
    uint64_t r = sm64(ctr++);
    float x = normal_from(r);
    float t = fmaf(cg, x, 1.0f);
    if (t <= 0.0f) continue;
    float v3 = t * t * t;
    uint64_t r2 = sm64(ctr++);
    float u3 = u01((uint32_t)(r2 >> 32));
    if (__logf(u3) < 0.5f * x * x + dg * (1.0f - v3 + __logf(v3))) return dg * v3;
  }
  return dg;
}
__device__ inline float wave_sum(float v) {
  #pragma unroll
  for (int o = 32; o > 0; o >>= 1) v += __shfl_down(v, o, 64);
  return __shfl(v, 0, 64);
}
__device__ inline float vmf_logc(float k) {
  float k2 = k * k;
  float sm = sqrtf(65280.25f + k2);
  float sp = sqrtf(65792.25f + k2);
  return 127.75f * (logf(255.5f + sm) + logf(255.5f + sp)) - 0.5f * (sm + sp);
}
__device__ inline unsigned short f2bf(float f) {
  uint32_t u = __float_as_uint(f);
  uint32_t r = (u + 0x7FFFu + ((u >> 16) & 1u)) >> 16;
  return (unsigned short)r;
}
__device__ inline float bf2f(unsigned short s) {
  return __uint_as_float(((uint32_t)s) << 16);
}
__device__ inline void async16(const unsigned short* g, unsigned short* l) {
  __builtin_amdgcn_global_load_lds(
      (const __attribute__((address_space(1))) unsigned int*)g,
      (__attribute__((address_space(3))) unsigned int*)l, 16, 0, 0);
}

// ---------------- kernels ----------------
// prep_w: normalize class means -> bf16, per-class params (A2,B2,lcw),
// plus zeroing of out (128 float4 per block * 8192 = exactly 512*8192 fp32)
// and rowsum. NO max-shift: exp(lcw-lkk) spans ~e^-11..e^11, safe in fp32.
__global__ __launch_bounds__(256) void prep_w(const float* __restrict__ weight,
                                              const float* __restrict__ lscale,
                                              unsigned short* __restrict__ muWb,
                                              float4* __restrict__ cparams,
                                              float* __restrict__ rowsum,
                                              float4* __restrict__ out4) {
  __shared__ float red[4];
  int c = blockIdx.x, tid = threadIdx.x;
  if (tid < 128) out4[(size_t)c * 128 + tid] = make_float4(0.f, 0.f, 0.f, 0.f);
  if (c < 20) rowsum[c * 256 + tid] = 0.0f;   // 20*256 = 5120

  const float* wr = weight + (size_t)c * (DIMD + 2) + 1;
  float v0 = wr[tid], v1 = wr[tid + 256];
  float s = wave_sum(v0 * v0 + v1 * v1);
  if ((tid & 63) == 0) red[tid >> 6] = s;
  __syncthreads();
  float tot = red[0] + red[1] + red[2] + red[3];
  float inv = rsqrtf(tot);
  muWb[(size_t)c * DIMD + tid]       = f2bf(v0 * inv);
  muWb[(size_t)c * DIMD + tid + 256] = f2bf(v1 * inv);
  if (tid == 0) {
    float hik = weight[(size_t)c * (DIMD + 2) + DIMD + 1];
    float kw = expf(-hik);
    float k1 = expf(lscale[0]);
    float lw = vmf_logc(kw);
    cparams[c] = make_float4(fmaf(k1, k1, kw * kw), 2.0f * k1 * kw, lw, 0.0f);
  }
}

// sample: 4 rows per block (1 wave per row). Fuses x-normalization.
// Rejection trials run in PARALLEL across lanes 0..31; first accepted wins.
__global__ __launch_bounds__(256) void sample_kernel(const float* __restrict__ params,
                                                     unsigned short* __restrict__ Sb) {
  int wave = threadIdx.x >> 6, lane = threadIdx.x & 63;
  int row = blockIdx.x * 4 + wave;          // b*KSAMP + k
  int b = row / KSAMP;
  const float* pr = params + (size_t)b * (DIMD + 2) + 1;

  float mu[8];
  float n2 = 0.0f;
  #pragma unroll
  for (int j = 0; j < 8; j++) { mu[j] = pr[j * 64 + lane]; n2 += mu[j] * mu[j]; }
  n2 = wave_sum(n2);
  float invn = rsqrtf(n2);
  #pragma unroll
  for (int j = 0; j < 8; j++) mu[j] *= invn;

  float kap = __expf(-pr[DIMD]);            // hidden_ik at col 513
  float bb = (-2.0f * kap + sqrtf(fmaf(4.0f * kap, kap, 511.0f * 511.0f))) / 511.0f;
  float x0 = (1.0f - bb) / (1.0f + bb);
  float cc = kap * x0 + 511.0f * __logf(1.0f - x0 * x0);

  // parallel trials: lane t in [0,32)
  uint64_t ctr = (((uint64_t)(row + 1)) << 32) | ((uint64_t)lane << 8);
  float g1 = gamma255(ctr);
  float g2 = gamma255(ctr);
  float z = g1 / (g1 + g2);
  float wt = (1.0f - (1.0f + bb) * z) / (1.0f - (1.0f - bb) * z);
  uint64_t r = sm64(ctr++);
  float u = u01((uint32_t)(r >> 32));
  float lhs = kap * wt + 511.0f * __logf(1.0f - x0 * wt) - cc;
  bool acc = (lane < TREJ) && (lhs >= __logf(fmaxf(u, 1e-10f)));
  uint64_t mask = __ballot(acc);
  int sel = mask ? (__ffsll((unsigned long long)mask) - 1) : 0;
  float w = __shfl(wt, sel, 64);

  // tangent direction
  uint64_t cbase = (((uint64_t)(row + 1)) << 32) | 0x40000000ull;
  float v[8];
  #pragma unroll
  for (int j = 0; j < 8; j++) v[j] = normal_from(sm64(cbase + (uint64_t)(j * 64 + lane)));
  float d = 0.0f;
  #pragma unroll
  for (int j = 0; j < 8; j++) d += v[j] * mu[j];
  d = wave_sum(d);
  float t2 = 0.0f;
  #pragma unroll
  for (int j = 0; j < 8; j++) { v[j] -= d * mu[j]; t2 += v[j] * v[j]; }
  t2 = wave_sum(t2);
  float ivt = rsqrtf(t2);
  float st = sqrtf(fmaxf(0.0f, 1.0f - w * w)) * ivt;
  float sv[8];
  float s2 = 0.0f;
  #pragma unroll
  for (int j = 0; j < 8; j++) { sv[j] = fmaf(st, v[j], w * mu[j]); s2 += sv[j] * sv[j]; }
  s2 = wave_sum(s2);
  float is = rsqrtf(s2);
  #pragma unroll
  for (int j = 0; j < 8; j++) Sb[(size_t)row * DIMD + j * 64 + lane] = f2bf(sv[j] * is);
}

// MFMA GEMM (bf16, 256x128 tile, BK=32), ping-pong LDS double-buffer, one
// barrier per K-iter. Each wave: 64 rows x 128 cols = 32 MFMA per iter vs
// 12 ds_read_b128 -> 2x the MFMA:overhead ratio of the 128x128 tile.
__global__ __launch_bounds__(256, 2) void gemm_lse(const unsigned short* __restrict__ Sb,
                                                   const unsigned short* __restrict__ Wb,
                                                   const float4* __restrict__ cparams,
                                                   float* __restrict__ rowsum) {
  __shared__ __align__(16) unsigned short As[2][256 * 32];   // 2 x 16 KB
  __shared__ __align__(16) unsigned short Bs[2][128 * 32];   // 2 x 8 KB
  int tid = threadIdx.x;
  int lane = tid & 63, wave = tid >> 6;
  int tx = lane & 15, tz = lane >> 4;
  int c0 = blockIdx.x * 128;
  int r0 = blockIdx.y * 256;

  // staging geometry: chunk = 16 rows = 1024B (64 lanes x 16B)
  int srow = (lane >> 2);                       // 0..15 within chunk
  int kg   = (lane & 3) ^ ((lane >> 3) & 3);    // swizzled k-group (verified 0-conflict)
  int chA0 = wave * 4;                          // A: 16 chunks, 4 per wave
  int chB0 = wave * 2;                          // B: 8 chunks, 2 per wave

  f32x4 acc[4][8];
  #pragma unroll
  for (int i = 0; i < 4; i++)
    #pragma unroll
    for (int j = 0; j < 8; j++) acc[i][j] = (f32x4){0.f, 0.f, 0.f, 0.f};

  // prologue: stage kt=0 into buffer 0
  #pragma unroll
  for (int c = 0; c < 4; c++) {
    int ch = chA0 + c, rowi = ch * 16 + srow;
    async16(&Sb[(size_t)(r0 + rowi) * DIMD + kg * 8], &As[0][ch * 512]);
  }
  #pragma unroll
  for (int c = 0; c < 2; c++) {
    int ch = chB0 + c, rowi = ch * 16 + srow;
    async16(&Wb[(size_t)(c0 + rowi) * DIMD + kg * 8], &Bs[0][ch * 512]);
  }

  int p = 0;
  for (int kt = 0; kt < DIMD; kt += 32) {
    __syncthreads();   // publishes buf[p]; drains loads issued a full iter ago
    if (kt + 32 < DIMD) {
      #pragma unroll
      for (int c = 0; c < 4; c++) {
        int ch = chA0 + c, rowi = ch * 16 + srow;
        async16(&Sb[(size_t)(r0 + rowi) * DIMD + kt + 32 + kg * 8], &As[p ^ 1][ch * 512]);
      }
      #pragma unroll
      for (int c = 0; c < 2; c++) {
        int ch = chB0 + c, rowi = ch * 16 + srow;
        async16(&Wb[(size_t)(c0 + rowi) * DIMD + kt + 32 + kg * 8], &Bs[p ^ 1][ch * 512]);
      }
    }
    bf16x8 af[4], bf[8];
    int sA = tz ^ ((tx >> 1) & 3);
    #pragma unroll
    for (int mi = 0; mi < 4; mi++) {
      int rA = wave * 64 + mi * 16 + tx;
      af[mi] = *(const bf16x8*)&As[p][rA * 32 + sA * 8];
    }
    #pragma unroll
    for (int ni = 0; ni < 8; ni++) {
      int rB = ni * 16 + tx;
      bf[ni] = *(const bf16x8*)&Bs[p][rB * 32 + sA * 8];
    }
    #pragma unroll
    for (int mi = 0; mi < 4; mi++)
      #pragma unroll
      for (int ni = 0; ni < 8; ni++)
        acc[mi][ni] = __builtin_amdgcn_mfma_f32_16x16x32_bf16(af[mi], bf[ni], acc[mi][ni], 0, 0, 0);
    p ^= 1;
  }

  // epilogue: kk2 = A2 + B2*cos; lkk ~ 255.5*log(255.5+sm) - sm + quad(sm)
  float4 cp[8];
  #pragma unroll
  for (int ni = 0; ni < 8; ni++) cp[ni] = cparams[c0 + ni * 16 + tx];

  const float CQ2 = -1.3435e-7f, CQ1 = 3.29348e-4f, CQ0 = -0.298669f;
  #pragma unroll
  for (int mi = 0; mi < 4; mi++) {
    #pragma unroll
    for (int reg = 0; reg < 4; reg++) {
      float s = 0.0f;
      #pragma unroll
      for (int ni = 0; ni < 8; ni++) {
        float cosv = acc[mi][ni][reg];
        float kk2 = fmaf(cp[ni].y, cosv, cp[ni].x);
        float sm = sqrtf(65280.25f + kk2);
        float lkk = fmaf(255.5f, __logf(255.5f + sm), -sm)
                  + fmaf(sm, fmaf(sm, CQ2, CQ1), CQ0);
        s += __expf(cp[ni].z - lkk);
      }
      #pragma unroll
      for (int o = 1; o < 16; o <<= 1) s += __shfl_xor(s, o, 64);
      if (tx == 0)
        atomicAdd(&rowsum[r0 + wave * 64 + mi * 16 + tz * 4 + reg], s);
    }
  }
}

// finalize: renormalizes mu_x from params directly
__global__ __launch_bounds__(64) void finalize_kernel(const float* __restrict__ params,
                                                      const unsigned short* __restrict__ muWb,
                                                      const float* __restrict__ rowsum,
                                                      const int* __restrict__ labels,
                                                      const float* __restrict__ lscale,
                                                      float* __restrict__ out) {
  int b = blockIdx.x;
  int lane = threadIdx.x;
  int lab = labels[b];
  const float* pr = params + (size_t)b * (DIMD + 2) + 1;
  float xv[8];
  float n2 = 0.0f;
  #pragma unroll
  for (int j = 0; j < 8; j++) { xv[j] = pr[j * 64 + lane]; n2 += xv[j] * xv[j]; }
  n2 = wave_sum(n2);
  float invn = rsqrtf(n2);
  float d = 0.0f;
  #pragma unroll
  for (int j = 0; j < 8; j++)
    d += xv[j] * invn * bf2f(muWb[(size_t)lab * DIMD + j * 64 + lane]);
  d = wave_sum(d);
  if (lane == 0) {
    float k1 = expf(lscale[0]);
    float acc = 0.0f;
    #pragma unroll
    for (int k = 0; k < KSAMP; k++) acc += __logf(rowsum[b * KSAMP + k]);
    float loss = acc * (1.0f / KSAMP) - k1 * d;
    out[(size_t)b * NCLS + lab] = -loss;
  }
}

// ---------------- launch ----------------
extern "C" void kernel_launch(void* const* d_in, const int* in_sizes, int n_in,
                              void* d_out, int out_size, void* d_ws, size_t ws_size,
                              hipStream_t stream) {
  const float* params = (const float*)d_in[0];
  const float* weight = (const float*)d_in[1];
  const float* lscale = (const float*)d_in[2];
  const int*   labels = (const int*)d_in[3];
  float* out = (float*)d_out;
  char* ws = (char*)d_ws;

  unsigned short* muWb   = (unsigned short*)(ws);                   // 8192*512*2  = 8,388,608
  unsigned short* Sb     = (unsigned short*)(ws + 8388608);         // 5120*512*2  = 5,242,880
  float4*         cparams= (float4*)(ws + 13631488);                // 8192*16     =   131,072
  float*          rowsum = (float*)(ws + 13762560);                 // 5120*4      =    20,480

  hipLaunchKernelGGL(prep_w, dim3(NCLS), dim3(256), 0, stream,
                     weight, lscale, muWb, cparams, rowsum, (float4*)out);
  hipLaunchKernelGGL(sample_kernel, dim3(BATCH * KSAMP / 4), dim3(256), 0, stream,
                     params, Sb);
  hipLaunchKernelGGL(gemm_lse, dim3(NCLS / 128, BATCH * KSAMP / 256), dim3(256), 0, stream,
                     Sb, muWb, cparams, rowsum);
  hipLaunchKernelGGL(finalize_kernel, dim3(BATCH), dim3(64), 0, stream,
                     params, muWb, rowsum, labels, lscale, out);
}